// Round 1
// baseline (306.310 us; speedup 1.0000x reference)
//
#include <hip/hip_runtime.h>
#include <hip/hip_bf16.h>

typedef _Float16 f16x8 __attribute__((ext_vector_type(8)));
typedef _Float16 f16x4 __attribute__((ext_vector_type(4)));
typedef float f32x4 __attribute__((ext_vector_type(4)));

#define SD 1024              // D == A == 1024
#define SEQ 2048
#define NB 32
#define M_TOTAL (NB * SEQ)   // 65536
#define BM 64
#define LDS_KEY_BYTES (BM * SD * 2)          // 131072
#define LDS_TOTAL (LDS_KEY_BYTES + 8*64*4)   // 133120

__device__ __forceinline__ float tanh_fast(float x) {
  float e = __expf(2.0f * x);
  return 1.0f - 2.0f / (e + 1.0f);   // robust: x->+inf gives 1, x->-inf gives -1
}

// qpb[b][a] = sum_d query[b][d]*Wq[d][a] + bq[a] + bk[a]
__global__ void k_qproj(const float* __restrict__ query, const float* __restrict__ Wq,
                        const float* __restrict__ bq, const float* __restrict__ bk,
                        float* __restrict__ qpb) {
  const int a = blockIdx.x * 256 + threadIdx.x;
  const int b = blockIdx.y;
  const float* q = query + b * SD;
  float s = 0.f;
#pragma unroll 8
  for (int d = 0; d < SD; ++d) s = fmaf(q[d], Wq[d * SD + a], s);
  qpb[b * SD + a] = s + bq[a] + bk[a];
}

// Pack Wk (f32 [K=1024][N=1024]) into fp16 MFMA-B fragment order:
// flat = ((nt*32 + kk)*64 + l)*8 + j  with n = nt*16 + (l&15), k = kk*32 + (l>>4)*8 + j
__global__ void k_packWk(const float* __restrict__ Wk, _Float16* __restrict__ WkB) {
  const int idx = blockIdx.x * 256 + threadIdx.x;   // 0..1048575
  const int k = idx >> 10, n = idx & 1023;
  const int nt = n >> 4, kk = k >> 5;
  const int l = (((k >> 3) & 3) << 4) | (n & 15);
  const int j = k & 7;
  WkB[((((nt << 5) + kk) << 6) + l) * 8 + j] = (_Float16)Wk[idx];
}

// Main: logits[m] = sum_n tanh( (key[m,:] @ Wk)[n] + qpb[b][n] ) * Wa[n]
__global__ __launch_bounds__(512, 2) void k_main(
    const float* __restrict__ key, const _Float16* __restrict__ WkB,
    const float* __restrict__ qpb, const float* __restrict__ Wa,
    float* __restrict__ logits) {
  extern __shared__ char lds[];
  float* red = (float*)(lds + LDS_KEY_BYTES);
  const int tid = threadIdx.x;
  const int wave = tid >> 6;
  const int lane = tid & 63;
  const int m0 = blockIdx.x * BM;
  const int b = m0 >> 11;          // S = 2048 rows per batch

  // ---- stage 64 key rows -> LDS fp16, XOR-swizzled ----
  {
    const float4* kp = (const float4*)(key + (size_t)m0 * SD);
#pragma unroll 4
    for (int i = 0; i < 32; ++i) {            // 16384 float4 / 512 threads
      const int idx = i * 512 + tid;
      const float4 v = kp[idx];
      const int row = idx >> 8;               // 256 float4 per row
      const int c4 = idx & 255;
      f16x4 h;
      h[0] = (_Float16)v.x; h[1] = (_Float16)v.y;
      h[2] = (_Float16)v.z; h[3] = (_Float16)v.w;
      const int off = (row * 2048 + c4 * 8) ^ ((row & 7) << 4);
      *(f16x4*)(lds + off) = h;
    }
  }
  __syncthreads();

  const int lane15 = lane & 15;
  const int lq = lane >> 4;
  const int swz = (lane15 & 7) << 4;
  int abase[4];
#pragma unroll
  for (int mt = 0; mt < 4; ++mt)
    abase[mt] = (mt * 16 + lane15) * 2048 + lq * 16;

  const f16x8* WkB8 = (const f16x8*)WkB;
  const float* qpb_b = qpb + b * SD;

  float lp[16];
#pragma unroll
  for (int i = 0; i < 16; ++i) lp[i] = 0.f;

  for (int g = 0; g < 2; ++g) {
    const int ng0 = wave * 128 + g * 64;      // this wave+group covers cols [ng0, ng0+64)
    const int ntg0 = ng0 >> 4;
    f32x4 acc[4][4];
#pragma unroll
    for (int mt = 0; mt < 4; ++mt)
#pragma unroll
      for (int nt = 0; nt < 4; ++nt)
        acc[mt][nt] = (f32x4){0.f, 0.f, 0.f, 0.f};

    f16x8 af[2][4], bf[2][4];
#pragma unroll
    for (int mt = 0; mt < 4; ++mt)
      af[0][mt] = *(const f16x8*)(lds + ((abase[mt] + 0) ^ swz));
#pragma unroll
    for (int nt = 0; nt < 4; ++nt)
      bf[0][nt] = WkB8[(ntg0 + nt) * 2048 + lane];

#pragma unroll 2
    for (int kk = 0; kk < 32; ++kk) {
      const int cur = kk & 1, nxt = cur ^ 1;
      if (kk < 31) {
#pragma unroll
        for (int mt = 0; mt < 4; ++mt)
          af[nxt][mt] = *(const f16x8*)(lds + ((abase[mt] + (kk + 1) * 64) ^ swz));
#pragma unroll
        for (int nt = 0; nt < 4; ++nt)
          bf[nxt][nt] = WkB8[(ntg0 + nt) * 2048 + (kk + 1) * 64 + lane];
      }
#pragma unroll
      for (int mt = 0; mt < 4; ++mt)
#pragma unroll
        for (int nt = 0; nt < 4; ++nt)
          acc[mt][nt] = __builtin_amdgcn_mfma_f32_16x16x32_f16(
              af[cur][mt], bf[cur][nt], acc[mt][nt], 0, 0, 0);
    }

    // epilogue: tanh + Wa reduction for this 64-col group
#pragma unroll
    for (int nt = 0; nt < 4; ++nt) {
      const int col = ng0 + nt * 16 + lane15;
      const float qv = qpb_b[col];
      const float wv = Wa[col];
#pragma unroll
      for (int mt = 0; mt < 4; ++mt)
#pragma unroll
        for (int j = 0; j < 4; ++j) {
          const float t = tanh_fast(acc[mt][nt][j] + qv);
          lp[mt * 4 + j] = fmaf(t, wv, lp[mt * 4 + j]);
        }
    }
  }

  // reduce over the 16 lanes of each quarter (these are the 16 columns)
#pragma unroll
  for (int i = 0; i < 16; ++i) {
    float v = lp[i];
    v += __shfl_xor(v, 1, 16);
    v += __shfl_xor(v, 2, 16);
    v += __shfl_xor(v, 4, 16);
    v += __shfl_xor(v, 8, 16);
    lp[i] = v;
  }
  if (lane15 == 0) {
#pragma unroll
    for (int mt = 0; mt < 4; ++mt)
#pragma unroll
      for (int j = 0; j < 4; ++j)
        red[wave * 64 + mt * 16 + lq * 4 + j] = lp[mt * 4 + j];
  }
  __syncthreads();
  if (tid < BM) {
    float s = 0.f;
#pragma unroll
    for (int w = 0; w < 8; ++w) s += red[w * 64 + tid];
    logits[m0 + tid] = s;
  }
}

// in-place softmax over S per batch row (att holds logits on entry)
__global__ void k_softmax(float* __restrict__ att) {
  const int b = blockIdx.x, t = threadIdx.x;
  __shared__ float red[4];
  float* row = att + b * SEQ;
  float v[8];
  float mx = -3.0e38f;
#pragma unroll
  for (int i = 0; i < 8; ++i) { v[i] = row[i * 256 + t]; mx = fmaxf(mx, v[i]); }
#pragma unroll
  for (int m = 1; m < 64; m <<= 1) mx = fmaxf(mx, __shfl_xor(mx, m, 64));
  if ((t & 63) == 0) red[t >> 6] = mx;
  __syncthreads();
  mx = fmaxf(fmaxf(red[0], red[1]), fmaxf(red[2], red[3]));
  __syncthreads();
  float s = 0.f;
#pragma unroll
  for (int i = 0; i < 8; ++i) { v[i] = __expf(v[i] - mx); s += v[i]; }
#pragma unroll
  for (int m = 1; m < 64; m <<= 1) s += __shfl_xor(s, m, 64);
  if ((t & 63) == 0) red[t >> 6] = s;
  __syncthreads();
  s = red[0] + red[1] + red[2] + red[3];
  const float inv = 1.0f / s;
#pragma unroll
  for (int i = 0; i < 8; ++i) row[i * 256 + t] = v[i] * inv;
}

// context partials: 16 s-slices per batch
__global__ void k_ctx(const float* __restrict__ value, const float* __restrict__ att,
                      float4* __restrict__ partials) {
  const int bx = blockIdx.x;
  const int b = bx >> 4, sl = bx & 15;
  const int t = threadIdx.x;                  // 256 threads -> 1024 d as float4
  const float4* vp = (const float4*)(value + (size_t)(b * SEQ + sl * 128) * SD);
  const float* ap = att + b * SEQ + sl * 128;
  float4 acc = make_float4(0.f, 0.f, 0.f, 0.f);
#pragma unroll 4
  for (int s = 0; s < 128; ++s) {
    const float w = ap[s];
    const float4 v = vp[s * 256 + t];
    acc.x = fmaf(w, v.x, acc.x); acc.y = fmaf(w, v.y, acc.y);
    acc.z = fmaf(w, v.z, acc.z); acc.w = fmaf(w, v.w, acc.w);
  }
  partials[(b * 16 + sl) * 256 + t] = acc;
}

__global__ void k_fin(const float* __restrict__ partials, float* __restrict__ ctx) {
  const int i = blockIdx.x * 256 + threadIdx.x;  // 0..32767
  const int b = i >> 10, d = i & 1023;
  float s = 0.f;
#pragma unroll
  for (int sl = 0; sl < 16; ++sl) s += partials[(b * 16 + sl) * SD + d];
  ctx[i] = s;
}

extern "C" void kernel_launch(void* const* d_in, const int* in_sizes, int n_in,
                              void* d_out, int out_size, void* d_ws, size_t ws_size,
                              hipStream_t stream) {
  const float* query = (const float*)d_in[0];
  const float* key   = (const float*)d_in[1];
  const float* value = (const float*)d_in[2];
  const float* Wq    = (const float*)d_in[3];
  const float* bq    = (const float*)d_in[4];
  const float* Wk    = (const float*)d_in[5];
  const float* bk    = (const float*)d_in[6];
  const float* Wa    = (const float*)d_in[7];
  // ba (d_in[8]) is softmax-invariant -> dropped.

  float* out = (float*)d_out;
  float* ctx_out = out;               // [32][1024]
  float* att_out = out + NB * SD;     // [32][2048]  (holds logits, then softmax in-place)

  char* ws = (char*)d_ws;
  float* qpb = (float*)ws;                         // 128 KB
  _Float16* WkB = (_Float16*)(ws + 131072);        // 2 MB
  float* partials = (float*)(ws + 131072);         // aliases WkB; disjoint lifetime

  hipFuncSetAttribute(reinterpret_cast<const void*>(k_main),
                      hipFuncAttributeMaxDynamicSharedMemorySize, LDS_TOTAL);

  k_qproj<<<dim3(4, NB), 256, 0, stream>>>(query, Wq, bq, bk, qpb);
  k_packWk<<<4096, 256, 0, stream>>>(Wk, WkB);
  k_main<<<M_TOTAL / BM, 512, LDS_TOTAL, stream>>>(key, WkB, qpb, Wa, att_out);
  k_softmax<<<NB, 256, 0, stream>>>(att_out);
  k_ctx<<<NB * 16, 256, 0, stream>>>(value, att_out, (float4*)partials);
  k_fin<<<NB * SD / 256, 256, 0, stream>>>(partials, ctx_out);
}